// Round 1
// baseline (90.906 us; speedup 1.0000x reference)
//
#include <hip/hip_runtime.h>

// Problem constants (B=2, H=4 -> NBH=8; Tq=Tk=512; D=64; HID=128)
#define T    512
#define D    64
#define HID  128
#define NBH  8
#define NP   (HID / 2)   // 64 c-pairs

typedef _Float16 h2 __attribute__((ext_vector_type(2)));

static __device__ __forceinline__ h2 bc_h2(float f) {
    return __builtin_bit_cast(h2, f);
}

// ---------------------------------------------------------------------------
// Phase A: qh[bh][c][i] = b1[c] + sum_d q[bh][i][d] * W1[d][c]   (src==0)
//          kh[bh][c][j] =         sum_d k[bh][j][d] * W1[64+d][c] (src==1)
// Output packed as h2 pairs over c: ws[bh][p][i], i contiguous.
// UNCHANGED from previous round (isolating the score-occupancy variable).
// grid: 8 bh x 2 src x 8 row-chunks x 4 c-splits = 512 blocks.
// ---------------------------------------------------------------------------
__global__ __launch_bounds__(256, 2) void proj_kernel(
    const float* __restrict__ q, const float* __restrict__ k,
    const float* __restrict__ W1, const float* __restrict__ b1,
    h2* __restrict__ qh_h, h2* __restrict__ kh_h)
{
    const int bid    = blockIdx.x;        // [0,512)
    const int bh     = bid >> 6;
    const int src    = (bid >> 5) & 1;
    const int chunk  = (bid >> 2) & 7;
    const int csplit = bid & 3;
    const int base_c = csplit * 32;       // 32 channels per block

    const float* __restrict__ X = (src == 0) ? q : k;
    h2* __restrict__ outp       = (src == 0) ? qh_h : kh_h;

    // 32 c-rows of W1, transposed to [cc][d]; stride 68 floats keeps 16 B
    // alignment (272 B) and breaks pow-2 bank stride on staging writes.
    __shared__ float w1t[32][68];

    const int tid = threadIdx.x;
    for (int idx = tid; idx < 32 * 64; idx += 256) {
        const int cc = idx & 31;          // consecutive -> coalesced global read
        const int d  = idx >> 5;
        w1t[cc][d] = W1[(src * D + d) * HID + base_c + cc];
    }
    __syncthreads();

    const int r  = tid & 63;              // lane -> row (stores coalesce)
    const int cg = tid >> 6;              // wave -> 8-c group (wave-uniform)
    const int i  = chunk * 64 + r;

    // This thread's input row in registers (64 VGPR).
    float xr[D];
    const float4* xrow = (const float4*)(X + (size_t)(bh * T + i) * D);
    #pragma unroll
    for (int t = 0; t < D / 4; ++t) {
        const float4 v = xrow[t];
        xr[4*t+0] = v.x; xr[4*t+1] = v.y; xr[4*t+2] = v.z; xr[4*t+3] = v.w;
    }

    #pragma unroll
    for (int pp = 0; pp < 4; ++pp) {
        const int cc0 = cg * 8 + 2 * pp;         // wave-uniform -> LDS broadcast
        float acc0 = (src == 0) ? b1[base_c + cc0]     : 0.0f;
        float acc1 = (src == 0) ? b1[base_c + cc0 + 1] : 0.0f;
        const float4* w0 = (const float4*)(&w1t[cc0][0]);
        const float4* w1 = (const float4*)(&w1t[cc0 + 1][0]);
        #pragma unroll
        for (int t = 0; t < D / 4; ++t) {
            const float4 a = w0[t];
            const float4 b = w1[t];
            acc0 += xr[4*t+0]*a.x + xr[4*t+1]*a.y + xr[4*t+2]*a.z + xr[4*t+3]*a.w;
            acc1 += xr[4*t+0]*b.x + xr[4*t+1]*b.y + xr[4*t+2]*b.z + xr[4*t+3]*b.w;
        }
        h2 v;
        v.x = (_Float16)acc0;
        v.y = (_Float16)acc1;
        const int p = csplit * 16 + cg * 4 + pp;  // global pair index [0,64)
        outp[(size_t)(bh * NP + p) * T + i] = v;  // lanes span i -> coalesced
    }
}

// ---------------------------------------------------------------------------
// Phase B: s[bh][i][j] = b2 + sum_c W2[c] * relu(qh[bh][c][i] + kh[bh][c][j])
// OCCUPANCY PROBE: 32x64 tile (was 64x64) -> grid 1024 blocks = 4 blocks/CU
// = 4 waves/SIMD (was 2). Total VALU work conserved; per-thread 2x4 fp32 acc.
// Inner: per c-pair per (m,n): v_pk_add_f16 + v_pk_max_f16 + v_dot2_f32_f16.
// Explicit 1-deep software pipeline retained; tiles padded +1 row so the
// prefetch needs no bounds branch.
// grid: 8 bh x 16 it x 8 jt = 1024 blocks.
// ---------------------------------------------------------------------------
__global__ __launch_bounds__(256, 4) void score_kernel(
    const h2* __restrict__ qh_h, const h2* __restrict__ kh_h,
    const float* __restrict__ W2, const float* __restrict__ b2,
    float* __restrict__ out)
{
    const int bid = blockIdx.x;           // [0, 1024)
    const int bh  = bid >> 7;             // [0,8)
    const int it  = (bid >> 3) & 15;      // [0,16) i-tiles of 32 rows
    const int jt  = bid & 7;              // [0,8)  j-tiles of 64 cols
    const int i0  = it * 32;
    const int j0  = jt * 64;

    __shared__ h2 qt2[NP + 1][32];        // +1 pad row: branch-free prefetch
    __shared__ h2 kt2[NP + 1][64];
    __shared__ h2 w2h[NP + 4];            // +4 pad pairs

    const int tid = threadIdx.x;
    // Stage q tile: 64 p-rows x 8 float4 (128 B coalesced per row).
    for (int idx = tid; idx < NP * 8; idx += 256) {
        const int p = idx >> 3;
        const int g = idx & 7;
        ((float4*)&qt2[p][0])[g] =
            ((const float4*)(qh_h + (size_t)(bh * NP + p) * T + i0))[g];
    }
    // Stage k tile: 64 p-rows x 16 float4 (256 B coalesced per row).
    for (int idx = tid; idx < NP * 16; idx += 256) {
        const int p = idx >> 4;
        const int g = idx & 15;
        ((float4*)&kt2[p][0])[g] =
            ((const float4*)(kh_h + (size_t)(bh * NP + p) * T + j0))[g];
    }
    if (tid < NP) {
        h2 w;
        w.x = (_Float16)W2[2 * tid];
        w.y = (_Float16)W2[2 * tid + 1];
        w2h[tid] = w;
    }
    __syncthreads();

    const int tx = tid & 15;              // j fragment: 4 cols
    const int ty = tid >> 4;              // i fragment: 2 rows (0..15)

    const h2* __restrict__ qb = &qt2[0][2 * ty];  // row stride 32 h2 = 128 B
    const h2* __restrict__ kb = &kt2[0][4 * tx];  // row stride 64 h2 = 256 B

    float acc[2][4];
    #pragma unroll
    for (int m = 0; m < 2; ++m)
        #pragma unroll
        for (int n = 0; n < 4; ++n)
            acc[m][n] = 0.0f;

    const h2 hzero = (h2)(_Float16)0.0f;

    // Pipeline primers.
    float2 qf = *(const float2*)qb;
    float4 kf = *(const float4*)kb;
    float4 w4 = *(const float4*)&w2h[0];

    for (int pg = 0; pg < 16; ++pg) {
        // Prefetch next w-group (pad pairs for pg==15; value unused).
        const float4 w4n = *(const float4*)&w2h[4 * pg + 4];
        #pragma unroll
        for (int s = 0; s < 4; ++s) {
            const int p = 4 * pg + s;
            // Prefetch p+1 fragments (pad row for p==63; value unused).
            const float2 qn = *(const float2*)(qb + (size_t)(p + 1) * 32);
            const float4 kn = *(const float4*)(kb + (size_t)(p + 1) * 64);

            const h2 w = bc_h2(s == 0 ? w4.x : s == 1 ? w4.y
                             : s == 2 ? w4.z : w4.w);
            const h2 qv[2] = {bc_h2(qf.x), bc_h2(qf.y)};
            const h2 kv[4] = {bc_h2(kf.x), bc_h2(kf.y), bc_h2(kf.z), bc_h2(kf.w)};
            #pragma unroll
            for (int m = 0; m < 2; ++m) {
                #pragma unroll
                for (int n = 0; n < 4; ++n) {
                    h2 u = qv[m] + kv[n];                    // v_pk_add_f16
                    u = __builtin_elementwise_max(u, hzero); // v_pk_max_f16
                    acc[m][n] = __builtin_amdgcn_fdot2(u, w, acc[m][n], false);
                }
            }
            qf = qn;
            kf = kn;
        }
        w4 = w4n;
    }

    const float bb = b2[0];
    #pragma unroll
    for (int m = 0; m < 2; ++m) {
        const int i = i0 + 2 * ty + m;
        float4 o;
        o.x = acc[m][0] + bb;
        o.y = acc[m][1] + bb;
        o.z = acc[m][2] + bb;
        o.w = acc[m][3] + bb;
        ((float4*)(out + (size_t)(bh * T + i) * T + j0))[tx] = o;
    }
}

extern "C" void kernel_launch(void* const* d_in, const int* in_sizes, int n_in,
                              void* d_out, int out_size, void* d_ws, size_t ws_size,
                              hipStream_t stream) {
    const float* q  = (const float*)d_in[0];
    const float* k  = (const float*)d_in[1];
    const float* W1 = (const float*)d_in[2];
    const float* b1 = (const float*)d_in[3];
    const float* W2 = (const float*)d_in[4];
    const float* b2 = (const float*)d_in[5];
    float* out = (float*)d_out;

    // Workspace: qh_h + kh_h as h2 pairs, each 8*64*512*4 B = 1 MB.
    h2* qh_h = (h2*)d_ws;
    h2* kh_h = qh_h + (size_t)NBH * NP * T;

    proj_kernel<<<512, 256, 0, stream>>>(q, k, W1, b1, qh_h, kh_h);
    score_kernel<<<1024, 256, 0, stream>>>(qh_h, kh_h, W2, b2, out);
}